// Round 3
// baseline (124.420 us; speedup 1.0000x reference)
//
#include <hip/hip_runtime.h>

// DRMM scoring kernel, round 3.
// Shapes: B=32, D=8, QL=16, DL=512, E=300, V=50000, 5 histogram bins.
// One block per (b,d) doc pair; 512 threads = 1 token per lane.
// Doc rows are read in 16-float (64B-line) stages, all 4 float4 loads of a
// stage issued together + 1-stage software pipeline: each cache line is
// fetched exactly once per lane with a full stage of compute as latency cover.
// Per-token dot/norm summation order is bit-identical to rounds 1-2 (passing).

constexpr int Bn  = 32;
constexpr int Dn  = 8;
constexpr int QLn = 16;
constexpr int DLn = 512;
constexpr int En  = 300;

__global__ __launch_bounds__(512) void drmm_score(
    const int*   __restrict__ bq,    // [B,QL]
    const int*   __restrict__ bd,    // [B,D,DL]
    const float* __restrict__ emb,   // [V,E]
    const float* __restrict__ w_g,   // [E]
    const float* __restrict__ b_g,   // [1]
    const float* __restrict__ w1,    // [5]
    const float* __restrict__ b1,    // [1]
    const float* __restrict__ w2,    // [1]
    const float* __restrict__ b2,    // [1]
    const float* __restrict__ w_o,   // [1]
    const float* __restrict__ b_o,   // [1]
    float*       __restrict__ out)   // [B*D]
{
    __shared__ __attribute__((aligned(16))) float q_lds[QLn * En]; // 19200 B
    __shared__ float pn_s[QLn][17];
    __shared__ float pg_s[QLn][17];
    __shared__ float qn_s[QLn];
    __shared__ float gate_s[QLn];
    __shared__ float tw_s[QLn];
    __shared__ unsigned long long hist_s[QLn]; // 5 x 12-bit packed counters per q
    __shared__ float wsum_s[QLn];

    const int n   = blockIdx.x;   // 0..255  (b*8 + d)
    const int b   = n >> 3;
    const int tid = threadIdx.x;  // 0..511

    // ---- Phase 1: stage query embeddings into LDS ----
    for (int idx = tid; idx < QLn * En; idx += 512) {
        const int  q   = idx / En;
        const int  e   = idx - q * En;
        const long tok = bq[b * QLn + q];
        q_lds[idx] = emb[tok * (long)En + e];
    }
    if (tid < QLn) hist_s[tid] = 0ull;
    __syncthreads();

    // ---- Phase 2: query norms + gate logits (16 threads per q) ----
    if (tid < 256) {
        const int q = tid >> 4, j = tid & 15;
        float pn = 0.f, pg = 0.f;
        for (int e = j; e < En; e += 16) {
            const float v = q_lds[q * En + e];
            pn = fmaf(v, v, pn);
            pg = fmaf(v, w_g[e], pg);
        }
        pn_s[q][j] = pn;
        pg_s[q][j] = pg;
    }
    __syncthreads();
    if (tid < QLn) {
        float sn = 0.f, sg = 0.f;
        for (int j = 0; j < 16; ++j) { sn += pn_s[tid][j]; sg += pg_s[tid][j]; }
        qn_s[tid]   = sqrtf(sn);
        gate_s[tid] = sg + b_g[0];
    }
    __syncthreads();
    if (tid == 0) {
        float m = gate_s[0];
        for (int q = 1; q < QLn; ++q) m = fmaxf(m, gate_s[q]);
        float ex[QLn];
        float s = 0.f;
        for (int q = 0; q < QLn; ++q) { ex[q] = expf(gate_s[q] - m); s += ex[q]; }
        for (int q = 0; q < QLn; ++q) tw_s[q] = ex[q] / s;
    }
    __syncthreads();

    // ---- Phase 3: per-token cosine sims vs all 16 query terms ----
    const long tok = bd[n * DLn + tid];
    const float* __restrict__ drow = emb + tok * (long)En;

    float acc[QLn];
#pragma unroll
    for (int q = 0; q < QLn; ++q) acc[q] = 0.f;
    float nrm = 0.f;

#define DRMM_CHUNK(dv, EE)                                                \
    do {                                                                  \
        nrm = fmaf((dv).x, (dv).x, nrm);                                  \
        nrm = fmaf((dv).y, (dv).y, nrm);                                  \
        nrm = fmaf((dv).z, (dv).z, nrm);                                  \
        nrm = fmaf((dv).w, (dv).w, nrm);                                  \
        _Pragma("unroll")                                                 \
        for (int q = 0; q < QLn; ++q) {                                   \
            const float4 qv =                                             \
                *reinterpret_cast<const float4*>(&q_lds[q * En + (EE)]);  \
            float a = acc[q];                                             \
            a = fmaf((dv).x, qv.x, a);                                    \
            a = fmaf((dv).y, qv.y, a);                                    \
            a = fmaf((dv).z, qv.z, a);                                    \
            a = fmaf((dv).w, qv.w, a);                                    \
            acc[q] = a;                                                   \
        }                                                                 \
    } while (0)

    // 16-float stages: 18 full stages (e=0..287) + 12-float tail (288..299).
    float4 P0 = *reinterpret_cast<const float4*>(drow + 0);
    float4 P1 = *reinterpret_cast<const float4*>(drow + 4);
    float4 P2 = *reinterpret_cast<const float4*>(drow + 8);
    float4 P3 = *reinterpret_cast<const float4*>(drow + 12);

    for (int s = 0; s < 18; ++s) {
        const int base = s * 16;
        float4 N0, N1, N2, N3;
        if (s < 17) {
            N0 = *reinterpret_cast<const float4*>(drow + base + 16);
            N1 = *reinterpret_cast<const float4*>(drow + base + 20);
            N2 = *reinterpret_cast<const float4*>(drow + base + 24);
            N3 = *reinterpret_cast<const float4*>(drow + base + 28);
        } else {  // tail stage: e = 288, 292, 296
            N0 = *reinterpret_cast<const float4*>(drow + 288);
            N1 = *reinterpret_cast<const float4*>(drow + 292);
            N2 = *reinterpret_cast<const float4*>(drow + 296);
            N3 = N2;  // unused
        }
        DRMM_CHUNK(P0, base + 0);
        DRMM_CHUNK(P1, base + 4);
        DRMM_CHUNK(P2, base + 8);
        DRMM_CHUNK(P3, base + 12);
        P0 = N0; P1 = N1; P2 = N2; P3 = N3;
    }
    DRMM_CHUNK(P0, 288);
    DRMM_CHUNK(P1, 292);
    DRMM_CHUNK(P2, 296);
#undef DRMM_CHUNK

    const float dn = sqrtf(nrm);
    unsigned long long cnt[QLn];
#pragma unroll
    for (int q = 0; q < QLn; ++q) {
        const float denom = fmaxf(qn_s[q] * dn, 1e-8f);
        const float c     = acc[q] / denom;
        // numpy.histogram semantics with edges [-1,-0.5,0,0.5,1,1]:
        // first 4 bins half-open [lo,hi), last bin closed [1.0,1.0].
        int bin = -1;
        if      (c >= -1.0f && c < -0.5f) bin = 0;
        else if (c >= -0.5f && c <  0.0f) bin = 1;
        else if (c >=  0.0f && c <  0.5f) bin = 2;
        else if (c >=  0.5f && c <  1.0f) bin = 3;
        else if (c ==  1.0f)              bin = 4;
        cnt[q] = (bin >= 0) ? (1ull << (12 * bin)) : 0ull;
    }

    // wave reduce the packed counters, then one LDS atomic per wave per q
    const int lane = tid & 63;
#pragma unroll
    for (int q = 0; q < QLn; ++q) {
        unsigned long long v = cnt[q];
        for (int off = 32; off > 0; off >>= 1) v += __shfl_down(v, off, 64);
        if (lane == 0) atomicAdd(&hist_s[q], v);
    }
    __syncthreads();

    // ---- Phase 4: ffnn + gated sum -> score ----
    if (tid < QLn) {
        const unsigned long long h = hist_s[tid];
        float f = 0.f;
        f = fmaf((float)((h >>  0) & 0xFFFull), w1[0], f);
        f = fmaf((float)((h >> 12) & 0xFFFull), w1[1], f);
        f = fmaf((float)((h >> 24) & 0xFFFull), w1[2], f);
        f = fmaf((float)((h >> 36) & 0xFFFull), w1[3], f);
        f = fmaf((float)((h >> 48) & 0xFFFull), w1[4], f);
        f += b1[0];
        f = f * w2[0] + b2[0];
        wsum_s[tid] = f * tw_s[tid];
    }
    __syncthreads();
    if (tid == 0) {
        float s = 0.f;
        for (int q = 0; q < QLn; ++q) s += wsum_s[q];
        out[n] = s * w_o[0] + b_o[0];
    }
}

extern "C" void kernel_launch(void* const* d_in, const int* in_sizes, int n_in,
                              void* d_out, int out_size, void* d_ws, size_t ws_size,
                              hipStream_t stream) {
    const int*   bq  = (const int*)  d_in[0];  // batch_queries
    // d_in[1] query_len: unused by reference
    const int*   bd  = (const int*)  d_in[2];  // batch_docs
    // d_in[3] doc_len: unused by reference
    const float* emb = (const float*)d_in[4];
    const float* w_g = (const float*)d_in[5];
    const float* b_g = (const float*)d_in[6];
    const float* w1  = (const float*)d_in[7];
    const float* b1  = (const float*)d_in[8];
    const float* w2  = (const float*)d_in[9];
    const float* b2  = (const float*)d_in[10];
    const float* w_o = (const float*)d_in[11];
    const float* b_o = (const float*)d_in[12];

    drmm_score<<<Bn * Dn, 512, 0, stream>>>(
        bq, bd, emb, w_g, b_g, w1, b1, w2, b2, w_o, b_o, (float*)d_out);
}

// Round 4
// 60.168 us; speedup vs baseline: 2.0679x; 2.0679x over previous
//
#include <hip/hip_runtime.h>

// DRMM scoring kernel, round 4.
// Shapes: B=32, D=8, QL=16, DL=512, E=300, V=50000, 5 histogram bins.
// One block per (b,d) doc pair; 256 threads, T=2 doc tokens per lane.
// Doc-row loads use a depth-5 circular-slot software pipeline with reload-in-
// place (NO register rotation -> no implicit per-iter vmcnt(0) drain; counted
// vmcnt waits let 10 loads/wave stay in flight across ~1500 cyc of issue).
// Per-token dot/norm summation order is bit-identical to rounds 1-3 (passing).

constexpr int Bn  = 32;
constexpr int Dn  = 8;
constexpr int QLn = 16;
constexpr int DLn = 512;
constexpr int En  = 300;

__global__ __launch_bounds__(256) void drmm_score(
    const int*   __restrict__ bq,    // [B,QL]
    const int*   __restrict__ bd,    // [B,D,DL]
    const float* __restrict__ emb,   // [V,E]
    const float* __restrict__ w_g,   // [E]
    const float* __restrict__ b_g,   // [1]
    const float* __restrict__ w1,    // [5]
    const float* __restrict__ b1,    // [1]
    const float* __restrict__ w2,    // [1]
    const float* __restrict__ b2,    // [1]
    const float* __restrict__ w_o,   // [1]
    const float* __restrict__ b_o,   // [1]
    float*       __restrict__ out)   // [B*D]
{
    __shared__ __attribute__((aligned(16))) float q_lds[QLn * En]; // 19200 B
    __shared__ float pn_s[QLn][17];
    __shared__ float pg_s[QLn][17];
    __shared__ float qn_s[QLn];
    __shared__ float gate_s[QLn];
    __shared__ float tw_s[QLn];
    __shared__ unsigned long long hist_s[QLn]; // 5 x 12-bit packed counters per q
    __shared__ float wsum_s[QLn];

    const int n   = blockIdx.x;   // 0..255  (b*8 + d)
    const int b   = n >> 3;
    const int tid = threadIdx.x;  // 0..255

    // ---- Phase 1: stage query embeddings into LDS (float4 granularity) ----
    for (int idx = tid; idx < QLn * (En / 4); idx += 256) {   // 1200 float4s
        const int  q   = idx / (En / 4);
        const int  c   = idx - q * (En / 4);
        const long tok = bq[b * QLn + q];
        *reinterpret_cast<float4*>(&q_lds[q * En + c * 4]) =
            *reinterpret_cast<const float4*>(emb + tok * (long)En + c * 4);
    }
    if (tid < QLn) hist_s[tid] = 0ull;
    __syncthreads();

    // ---- Phase 2: query norms + gate logits (16 threads per q) ----
    {
        const int q = tid >> 4, j = tid & 15;
        float pn = 0.f, pg = 0.f;
        for (int e = j; e < En; e += 16) {
            const float v = q_lds[q * En + e];
            pn = fmaf(v, v, pn);
            pg = fmaf(v, w_g[e], pg);
        }
        pn_s[q][j] = pn;
        pg_s[q][j] = pg;
    }
    __syncthreads();
    if (tid < QLn) {
        float sn = 0.f, sg = 0.f;
        for (int j = 0; j < 16; ++j) { sn += pn_s[tid][j]; sg += pg_s[tid][j]; }
        qn_s[tid]   = sqrtf(sn);
        gate_s[tid] = sg + b_g[0];
    }
    __syncthreads();
    if (tid == 0) {
        float m = gate_s[0];
        for (int q = 1; q < QLn; ++q) m = fmaxf(m, gate_s[q]);
        float ex[QLn];
        float s = 0.f;
        for (int q = 0; q < QLn; ++q) { ex[q] = expf(gate_s[q] - m); s += ex[q]; }
        for (int q = 0; q < QLn; ++q) tw_s[q] = ex[q] / s;
    }
    __syncthreads();

    // ---- Phase 3: per-token cosine sims; 2 tokens per lane ----
    const long tok0 = bd[n * DLn + tid];
    const long tok1 = bd[n * DLn + tid + 256];
    const float* __restrict__ r0 = emb + tok0 * (long)En;
    const float* __restrict__ r1 = emb + tok1 * (long)En;

    float acc0[QLn], acc1[QLn];
#pragma unroll
    for (int q = 0; q < QLn; ++q) { acc0[q] = 0.f; acc1[q] = 0.f; }
    float nr0 = 0.f, nr1 = 0.f;

    // compute one 4-float chunk for both tokens (order identical to rounds 1-3)
#define DRMM_CHUNK(d0, d1, EE)                                            \
    do {                                                                  \
        nr0 = fmaf((d0).x, (d0).x, nr0);                                  \
        nr0 = fmaf((d0).y, (d0).y, nr0);                                  \
        nr0 = fmaf((d0).z, (d0).z, nr0);                                  \
        nr0 = fmaf((d0).w, (d0).w, nr0);                                  \
        nr1 = fmaf((d1).x, (d1).x, nr1);                                  \
        nr1 = fmaf((d1).y, (d1).y, nr1);                                  \
        nr1 = fmaf((d1).z, (d1).z, nr1);                                  \
        nr1 = fmaf((d1).w, (d1).w, nr1);                                  \
        _Pragma("unroll")                                                 \
        for (int q = 0; q < QLn; ++q) {                                   \
            const float4 qv =                                             \
                *reinterpret_cast<const float4*>(&q_lds[q * En + (EE)]);  \
            float s0 = acc0[q];                                           \
            s0 = fmaf((d0).x, qv.x, s0);                                  \
            s0 = fmaf((d0).y, qv.y, s0);                                  \
            s0 = fmaf((d0).z, qv.z, s0);                                  \
            s0 = fmaf((d0).w, qv.w, s0);                                  \
            acc0[q] = s0;                                                 \
            float s1 = acc1[q];                                           \
            s1 = fmaf((d1).x, qv.x, s1);                                  \
            s1 = fmaf((d1).y, qv.y, s1);                                  \
            s1 = fmaf((d1).z, qv.z, s1);                                  \
            s1 = fmaf((d1).w, qv.w, s1);                                  \
            acc1[q] = s1;                                                 \
        }                                                                 \
    } while (0)

    // compute slot's chunk, then reload the SAME slot from 5 chunks ahead
#define DRMM_STEP_R(SA, SB, EE)                                           \
    do {                                                                  \
        DRMM_CHUNK(SA, SB, (EE));                                         \
        SA = *reinterpret_cast<const float4*>(r0 + (EE) + 20);            \
        SB = *reinterpret_cast<const float4*>(r1 + (EE) + 20);            \
    } while (0)

    // prologue: slots hold chunks 0..4 (10 loads in flight)
    float4 s0a = *reinterpret_cast<const float4*>(r0 + 0);
    float4 s1a = *reinterpret_cast<const float4*>(r1 + 0);
    float4 s0b = *reinterpret_cast<const float4*>(r0 + 4);
    float4 s1b = *reinterpret_cast<const float4*>(r1 + 4);
    float4 s0c = *reinterpret_cast<const float4*>(r0 + 8);
    float4 s1c = *reinterpret_cast<const float4*>(r1 + 8);
    float4 s0d = *reinterpret_cast<const float4*>(r0 + 12);
    float4 s1d = *reinterpret_cast<const float4*>(r1 + 12);
    float4 s0e = *reinterpret_cast<const float4*>(r0 + 16);
    float4 s1e = *reinterpret_cast<const float4*>(r1 + 16);

#pragma unroll 1
    for (int k = 0; k < 14; ++k) {          // chunks 0..69, reload 5..74
        const int e = k * 20;
        DRMM_STEP_R(s0a, s1a, e + 0);
        DRMM_STEP_R(s0b, s1b, e + 4);
        DRMM_STEP_R(s0c, s1c, e + 8);
        DRMM_STEP_R(s0d, s1d, e + 12);
        DRMM_STEP_R(s0e, s1e, e + 16);
    }
    // epilogue: chunks 70..74, no reload
    DRMM_CHUNK(s0a, s1a, 280);
    DRMM_CHUNK(s0b, s1b, 284);
    DRMM_CHUNK(s0c, s1c, 288);
    DRMM_CHUNK(s0d, s1d, 292);
    DRMM_CHUNK(s0e, s1e, 296);
#undef DRMM_STEP_R
#undef DRMM_CHUNK

    const float dn0 = sqrtf(nr0);
    const float dn1 = sqrtf(nr1);

    unsigned long long cnt[QLn];
#pragma unroll
    for (int q = 0; q < QLn; ++q) {
        unsigned long long v = 0ull;
        {
            const float denom = fmaxf(qn_s[q] * dn0, 1e-8f);
            const float c     = acc0[q] / denom;
            int bin = -1;
            if      (c >= -1.0f && c < -0.5f) bin = 0;
            else if (c >= -0.5f && c <  0.0f) bin = 1;
            else if (c >=  0.0f && c <  0.5f) bin = 2;
            else if (c >=  0.5f && c <  1.0f) bin = 3;
            else if (c ==  1.0f)              bin = 4;
            if (bin >= 0) v += 1ull << (12 * bin);
        }
        {
            const float denom = fmaxf(qn_s[q] * dn1, 1e-8f);
            const float c     = acc1[q] / denom;
            int bin = -1;
            if      (c >= -1.0f && c < -0.5f) bin = 0;
            else if (c >= -0.5f && c <  0.0f) bin = 1;
            else if (c >=  0.0f && c <  0.5f) bin = 2;
            else if (c >=  0.5f && c <  1.0f) bin = 3;
            else if (c ==  1.0f)              bin = 4;
            if (bin >= 0) v += 1ull << (12 * bin);
        }
        cnt[q] = v;
    }

    const int lane = tid & 63;
#pragma unroll
    for (int q = 0; q < QLn; ++q) {
        unsigned long long v = cnt[q];
        for (int off = 32; off > 0; off >>= 1) v += __shfl_down(v, off, 64);
        if (lane == 0) atomicAdd(&hist_s[q], v);
    }
    __syncthreads();

    // ---- Phase 4: ffnn + gated sum -> score ----
    if (tid < QLn) {
        const unsigned long long h = hist_s[tid];
        float f = 0.f;
        f = fmaf((float)((h >>  0) & 0xFFFull), w1[0], f);
        f = fmaf((float)((h >> 12) & 0xFFFull), w1[1], f);
        f = fmaf((float)((h >> 24) & 0xFFFull), w1[2], f);
        f = fmaf((float)((h >> 36) & 0xFFFull), w1[3], f);
        f = fmaf((float)((h >> 48) & 0xFFFull), w1[4], f);
        f += b1[0];
        f = f * w2[0] + b2[0];
        wsum_s[tid] = f * tw_s[tid];
    }
    __syncthreads();
    if (tid == 0) {
        float s = 0.f;
        for (int q = 0; q < QLn; ++q) s += wsum_s[q];
        out[n] = s * w_o[0] + b_o[0];
    }
}

extern "C" void kernel_launch(void* const* d_in, const int* in_sizes, int n_in,
                              void* d_out, int out_size, void* d_ws, size_t ws_size,
                              hipStream_t stream) {
    const int*   bq  = (const int*)  d_in[0];  // batch_queries
    // d_in[1] query_len: unused by reference
    const int*   bd  = (const int*)  d_in[2];  // batch_docs
    // d_in[3] doc_len: unused by reference
    const float* emb = (const float*)d_in[4];
    const float* w_g = (const float*)d_in[5];
    const float* b_g = (const float*)d_in[6];
    const float* w1  = (const float*)d_in[7];
    const float* b1  = (const float*)d_in[8];
    const float* w2  = (const float*)d_in[9];
    const float* b2  = (const float*)d_in[10];
    const float* w_o = (const float*)d_in[11];
    const float* b_o = (const float*)d_in[12];

    drmm_score<<<Bn * Dn, 256, 0, stream>>>(
        bq, bd, emb, w_g, b_g, w1, b1, w2, b2, w_o, b_o, (float*)d_out);
}